// Round 5
// baseline (419.258 us; speedup 1.0000x reference)
//
#include <hip/hip_runtime.h>

#define B_ 2
#define S_ 2048
#define H_ 16
#define HD_ 128
#define QKVROW 6144   // 3*2048, row length of qkv activation
#define M_ 4096       // B_*S_

typedef float f32x4 __attribute__((ext_vector_type(4)));
typedef __bf16 bf16x8 __attribute__((ext_vector_type(8)));
typedef unsigned short ushortx8 __attribute__((ext_vector_type(8)));

__device__ __forceinline__ float bf2f(unsigned short u) {
  union { unsigned u; float f; } v;
  v.u = ((unsigned)u) << 16;
  return v.f;
}
__device__ __forceinline__ unsigned short f2bf(float f) {
  union { __bf16 b; unsigned short u; } c;
  c.b = (__bf16)f;  // native v_cvt path
  return c.u;
}
// 8 contiguous fp32 -> 8 bf16 ushorts (vector loads + native cvt)
__device__ __forceinline__ ushortx8 cvt8(const float* f) {
  const f32x4 lo = *(const f32x4*)f;
  const f32x4 hi = *(const f32x4*)(f + 4);
  ushortx8 o;
#pragma unroll
  for (int t = 0; t < 4; ++t) o[t] = f2bf(lo[t]);
#pragma unroll
  for (int t = 0; t < 4; ++t) o[4 + t] = f2bf(hi[t]);
  return o;
}
// async global->LDS, 16B/lane. LDS dest = wave-uniform base + lane*16.
__device__ __forceinline__ void async16(const unsigned short* g, unsigned short* l) {
  __builtin_amdgcn_global_load_lds(
      (const __attribute__((address_space(1))) unsigned int*)g,
      (__attribute__((address_space(3))) unsigned int*)l, 16, 0, 0);
}

// ---------------------------------------------------------------------------
// One-time RoPE cos/sin table: tab[s][j] = {cos, sin}(s * base^(-j/64)).
// ---------------------------------------------------------------------------
__global__ __launch_bounds__(256) void rope_table(float* __restrict__ tab) {
  const int i = blockIdx.x * 256 + threadIdx.x;  // [0, 2048*64)
  const int s = i >> 6, t = i & 63;
  const float invf = expf(-(float)t * 0.14391156831212787f);  // ln(1e4)/64
  float sn, cs;
  sincosf((float)s * invf, &sn, &cs);
  tab[2 * i] = cs;
  tab[2 * i + 1] = sn;
}

// ---------------------------------------------------------------------------
// One-time fp32 -> bf16 conversion of x, Wqkv, wo in a single launch.
// ---------------------------------------------------------------------------
__global__ __launch_bounds__(256) void f2bf3(
    const float* __restrict__ a, unsigned short* __restrict__ da, int na8,
    const float* __restrict__ b, unsigned short* __restrict__ db, int nb8,
    const float* __restrict__ c, unsigned short* __restrict__ dc, int nc8) {
  const int ntot = na8 + nb8 + nc8;
  int i = blockIdx.x * 256 + threadIdx.x;
  const int stride = gridDim.x * 256;
  for (; i < ntot; i += stride) {
    const float* s;
    unsigned short* d;
    int off = i;
    if (off < na8) { s = a; d = da; }
    else if (off - na8 < nb8) { off -= na8; s = b; d = db; }
    else { off -= na8 + nb8; s = c; d = dc; }
    const ushortx8 o = cvt8(s + (size_t)off * 8);
    *(ushortx8*)&d[(size_t)off * 8] = o;
  }
}

// ---------------------------------------------------------------------------
// GEMM1: qkv[m,n] = sum_k xb[m,k]*wb[n,k] + b[n].  xb,wb bf16; C bf16.
// Round-2 verified compute body (128x128 tile, rule-21 swizzle) + T3/T4
// 2-deep pipeline: double-buffered LDS, counted vmcnt(8) across raw
// s_barriers (never 0 in steady state), stage(kt+2) issued after the tile's
// read barrier so loads hide under a full compute phase.
// ---------------------------------------------------------------------------
__global__ __launch_bounds__(256) void gemm1(
    const unsigned short* __restrict__ A, const unsigned short* __restrict__ Bm,
    const float* __restrict__ bias, unsigned short* __restrict__ C) {
  __shared__ unsigned short As[2][128 * 64];  // 32 KB
  __shared__ unsigned short Bs[2][128 * 64];  // 32 KB
  const int tid = threadIdx.x;
  const int lane = tid & 63, wave = tid >> 6;
  const int l15 = lane & 15, quad = lane >> 4;
  const int m0 = blockIdx.y * 128, n0 = blockIdx.x * 128;
  const int wr = (wave >> 1) * 64, wc = (wave & 1) * 64;

  f32x4 acc[4][4];
#pragma unroll
  for (int r = 0; r < 4; ++r)
#pragma unroll
    for (int c = 0; c < 4; ++c) acc[r][c] = (f32x4){0.f, 0.f, 0.f, 0.f};

  auto stage = [&](int t, int b) {  // 8 loads/wave: K-tile t -> buffer b
#pragma unroll
    for (int i = 0; i < 4; ++i) {
      const int c0 = wave * 256 + i * 64;   // 16B-unit base within tile
      const int u = c0 + lane;
      const int row = u >> 3, cu = u & 7;   // 128 rows x 8 units
      const int cs = cu ^ (row & 7);        // pre-swizzled source column
      async16(A + (size_t)(m0 + row) * 2048 + t * 64 + cs * 8, &As[b][c0 * 8]);
      async16(Bm + (size_t)(n0 + row) * 2048 + t * 64 + cs * 8, &Bs[b][c0 * 8]);
    }
  };

  stage(0, 0);
  stage(1, 1);

  for (int kt = 0; kt < 32; ++kt) {
    const int b = kt & 1;
    // per-wave: force this tile's 8 loads complete; next tile's 8 may fly
    if (kt < 31) asm volatile("s_waitcnt vmcnt(8)" ::: "memory");
    else         asm volatile("s_waitcnt vmcnt(0)" ::: "memory");
    __builtin_amdgcn_s_barrier();         // all waves' tile-kt data visible
    __builtin_amdgcn_sched_barrier(0);    // no ds_read hoists above this

#pragma unroll
    for (int s = 0; s < 2; ++s) {
      bf16x8 af[4], bf[4];
#pragma unroll
      for (int r = 0; r < 4; ++r) {
        const int row = wr + r * 16 + l15;
        af[r] = *(const bf16x8*)&As[b][row * 64 + (((s * 4 + quad) ^ (row & 7)) << 3)];
      }
#pragma unroll
      for (int c = 0; c < 4; ++c) {
        const int row = wc + c * 16 + l15;
        bf[c] = *(const bf16x8*)&Bs[b][row * 64 + (((s * 4 + quad) ^ (row & 7)) << 3)];
      }
#pragma unroll
      for (int r = 0; r < 4; ++r)
#pragma unroll
        for (int c = 0; c < 4; ++c)
          acc[r][c] = __builtin_amdgcn_mfma_f32_16x16x32_bf16(af[r], bf[c], acc[r][c], 0, 0, 0);
    }

    // all this wave's ds_reads done (MFMA consumers already issued);
    // close cross-wave hazard, then free buffer b for restaging.
    asm volatile("s_waitcnt lgkmcnt(0)" ::: "memory");
    __builtin_amdgcn_sched_barrier(0);
    __builtin_amdgcn_s_barrier();
    __builtin_amdgcn_sched_barrier(0);
    if (kt + 2 < 32) stage(kt + 2, b);
  }

#pragma unroll
  for (int c = 0; c < 4; ++c) {
    const int col = n0 + wc + c * 16 + l15;
    const float bv = bias[col];
#pragma unroll
    for (int r = 0; r < 4; ++r) {
      const int row = m0 + wr + r * 16 + quad * 4;
#pragma unroll
      for (int i = 0; i < 4; ++i)
        C[(size_t)(row + i) * QKVROW + col] = f2bf(acc[r][c][i] + bv);
    }
  }
}

// ---------------------------------------------------------------------------
// In-place deinterleave+RoPE on q,k slots of qkv (q pre-scaled by hd^-0.5);
// Vt [b,h,hd,s] from the v slot. Trig from the precomputed table.
// ---------------------------------------------------------------------------
__global__ __launch_bounds__(256) void rope_vt(
    unsigned short* qkv, unsigned short* __restrict__ Vt,
    const float* __restrict__ tab) {
  __shared__ unsigned short vs[64 * 136];
  const int b = blockIdx.z, h = blockIdx.y, s0 = blockIdx.x * 64;
  const int tid = threadIdx.x;
  const int r = tid >> 2, cpart = (tid & 3) * 32;
  const int s = s0 + r;
  unsigned short* base = qkv + (size_t)(b * S_ + s) * QKVROW + h * 384;
  const int j0 = cpart >> 1;

  ushortx8 ivq[4], ivk[4], ivv[4];
#pragma unroll
  for (int i = 0; i < 4; ++i) {
    ivq[i] = *(const ushortx8*)&base[cpart + i * 8];
    ivk[i] = *(const ushortx8*)&base[128 + cpart + i * 8];
    ivv[i] = *(const ushortx8*)&base[256 + cpart + i * 8];
  }

  float cs[16], sn[16];
  {
    const f32x4* tr = (const f32x4*)&tab[(size_t)s * 128 + j0 * 2];
#pragma unroll
    for (int t = 0; t < 8; ++t) {
      const f32x4 v = tr[t];  // {cos,sin,cos,sin}
      cs[2 * t] = v[0]; sn[2 * t] = v[1];
      cs[2 * t + 1] = v[2]; sn[2 * t + 1] = v[3];
    }
  }

  __syncthreads();  // all reads of q/k rows done before anyone writes them

#pragma unroll
  for (int which = 0; which < 2; ++which) {
    const ushortx8* iv = (which == 0) ? ivq : ivk;
    const float scale = (which == 0) ? 0.08838834764831845f : 1.0f;
    ushortx8 o1a, o1b, o2a, o2b;
#pragma unroll
    for (int t = 0; t < 16; ++t) {
      const float x1 = bf2f(iv[(2 * t) >> 3][(2 * t) & 7]);
      const float x2 = bf2f(iv[(2 * t + 1) >> 3][(2 * t + 1) & 7]);
      const unsigned short r1 = f2bf((x1 * cs[t] - x2 * sn[t]) * scale);
      const unsigned short r2 = f2bf((x2 * cs[t] + x1 * sn[t]) * scale);
      if (t < 8) { o1a[t] = r1; o2a[t] = r2; }
      else       { o1b[t - 8] = r1; o2b[t - 8] = r2; }
    }
    unsigned short* out = base + which * 128;
    *(ushortx8*)&out[j0] = o1a;
    *(ushortx8*)&out[j0 + 8] = o1b;
    *(ushortx8*)&out[64 + j0] = o2a;
    *(ushortx8*)&out[64 + j0 + 8] = o2b;
  }

#pragma unroll
  for (int i = 0; i < 4; ++i)
    *(ushortx8*)&vs[r * 136 + cpart + i * 8] = ivv[i];
  __syncthreads();
  const size_t vtb = (size_t)(b * H_ + h) * HD_ * S_ + s0;
#pragma unroll
  for (int it = 0; it < 4; ++it) {
    const int a = tid + it * 256;
    const int d = a >> 3, sc = (a & 7) * 8;
    ushortx8 o;
#pragma unroll
    for (int t = 0; t < 8; ++t) o[t] = vs[(sc + t) * 136 + d];
    *(ushortx8*)&Vt[vtb + (size_t)d * S_ + sc] = o;
  }
}

// ---------------------------------------------------------------------------
// Flash attention v3, causal. grid (8, 32), 512 threads (8 waves).
// Unchanged.
// ---------------------------------------------------------------------------
__global__ __launch_bounds__(512) void attn(
    unsigned short* qkv, const unsigned short* __restrict__ Vt) {
  __shared__ unsigned short Ks[64 * 136];   // 17.4 KB
  __shared__ unsigned short Vs[128 * 72];   // 18.4 KB
  __shared__ unsigned short Ps[8 * 16 * 72];// 18.4 KB (per-wave strips)
  const int p = blockIdx.x, bh = blockIdx.y;
  const int b = bh >> 4, h = bh & 15;
  const int tid = threadIdx.x, lane = tid & 63, wave = tid >> 6;
  const int l15 = lane & 15, quad = lane >> 4;

  unsigned short* qh = qkv + (size_t)b * S_ * QKVROW + h * 384;
  const unsigned short* Vb = Vt + (size_t)bh * HD_ * S_;
  unsigned short* Pw = &Ps[wave * 16 * 72];

  ushortx8 rk[2], rv[2];
  auto pref = [&](int j) {  // stage kv-64 tile j into regs
#pragma unroll
    for (int t = 0; t < 2; ++t) {
      const int uk = t * 512 + tid;
      const int krow = uk >> 4, kcu = uk & 15;  // 64 rows x 16 units
      rk[t] = *(const ushortx8*)(qh + (size_t)(j * 64 + krow) * QKVROW + 128 + kcu * 8);
      const int vrow = uk >> 3, vcu = uk & 7;   // 128 rows x 8 units
      rv[t] = *(const ushortx8*)(Vb + (size_t)vrow * S_ + j * 64 + vcu * 8);
    }
  };
  pref(0);

#pragma unroll
  for (int half = 0; half < 2; ++half) {
    const int qt = half ? 15 - p : p;   // short tile first, then long
    const int jN = 2 * qt + 2;          // kv-64 tiles needed

    bf16x8 aq[4];
#pragma unroll
    for (int ks = 0; ks < 4; ++ks)
      aq[ks] = *(const bf16x8*)&qh[(size_t)(qt * 128 + wave * 16 + l15) * QKVROW +
                                   ks * 32 + quad * 8];

    f32x4 o[8];
    float mrow[4], lrow[4];
#pragma unroll
    for (int ct = 0; ct < 8; ++ct) o[ct] = (f32x4){0.f, 0.f, 0.f, 0.f};
#pragma unroll
    for (int i = 0; i < 4; ++i) { mrow[i] = -1e30f; lrow[i] = 0.f; }

    for (int j = 0; j < jN; ++j) {
      __syncthreads();  // all waves done reading Ks/Vs of previous tile
#pragma unroll
      for (int t = 0; t < 2; ++t) {
        const int uk = t * 512 + tid;
        *(ushortx8*)&Ks[(uk >> 4) * 136 + (uk & 15) * 8] = rk[t];
        *(ushortx8*)&Vs[(uk >> 3) * 72 + (uk & 7) * 8] = rv[t];
      }
      __syncthreads();  // tiles visible

      const int jn = (j + 1 < jN) ? j + 1 : (half == 0 ? 0 : -1);
      if (jn >= 0) pref(jn);  // overlaps MFMA/softmax below

      // S = Q K^T over this kv-64 tile (Q pre-scaled by hd^-0.5)
      f32x4 sacc[4];
#pragma unroll
      for (int ct = 0; ct < 4; ++ct) sacc[ct] = (f32x4){0.f, 0.f, 0.f, 0.f};
#pragma unroll
      for (int ks = 0; ks < 4; ++ks) {
        bf16x8 bk[4];
#pragma unroll
        for (int ct = 0; ct < 4; ++ct)
          bk[ct] = *(const bf16x8*)&Ks[(ct * 16 + l15) * 136 + ks * 32 + quad * 8];
#pragma unroll
        for (int ct = 0; ct < 4; ++ct)
          sacc[ct] = __builtin_amdgcn_mfma_f32_16x16x32_bf16(aq[ks], bk[ct], sacc[ct], 0, 0, 0);
      }

      if (j >= 2 * qt) {  // diagonal region: mask gcol > grow
#pragma unroll
        for (int ct = 0; ct < 4; ++ct)
#pragma unroll
          for (int i = 0; i < 4; ++i) {
            const int grow = qt * 128 + wave * 16 + quad * 4 + i;
            const int gcol = j * 64 + ct * 16 + l15;
            if (gcol > grow) sacc[ct][i] = -1e30f;
          }
      }

      // online softmax (16 rows/wave = quad*4+i; reduce over 16 lanes)
#pragma unroll
      for (int i = 0; i < 4; ++i) {
        float m = sacc[0][i];
#pragma unroll
        for (int ct = 1; ct < 4; ++ct) m = fmaxf(m, sacc[ct][i]);
#pragma unroll
        for (int off = 1; off < 16; off <<= 1) m = fmaxf(m, __shfl_xor(m, off));
        const float mn = fmaxf(mrow[i], m);
        const float alpha = __expf(mrow[i] - mn);
        mrow[i] = mn;
        float rsum = 0.f;
#pragma unroll
        for (int ct = 0; ct < 4; ++ct) {
          const float pv = __expf(sacc[ct][i] - mn);
          sacc[ct][i] = pv;
          rsum += pv;
        }
#pragma unroll
        for (int off = 1; off < 16; off <<= 1) rsum += __shfl_xor(rsum, off);
        lrow[i] = lrow[i] * alpha + rsum;
#pragma unroll
        for (int ct = 0; ct < 8; ++ct) o[ct][i] *= alpha;
      }

      // P into wave-private strip (C-layout -> A-layout); no barrier needed
#pragma unroll
      for (int ct = 0; ct < 4; ++ct)
#pragma unroll
        for (int i = 0; i < 4; ++i)
          Pw[(quad * 4 + i) * 72 + ct * 16 + l15] = f2bf(sacc[ct][i]);

      // O += P * V
#pragma unroll
      for (int ks = 0; ks < 2; ++ks) {
        const bf16x8 ap = *(const bf16x8*)&Pw[l15 * 72 + ks * 32 + quad * 8];
        bf16x8 bv[8];
#pragma unroll
        for (int ct = 0; ct < 8; ++ct)
          bv[ct] = *(const bf16x8*)&Vs[(ct * 16 + l15) * 72 + ks * 32 + quad * 8];
#pragma unroll
        for (int ct = 0; ct < 8; ++ct)
          o[ct] = __builtin_amdgcn_mfma_f32_16x16x32_bf16(ap, bv[ct], o[ct], 0, 0, 0);
      }
    }

    // write ctx into the (consumed, block-private) q slot
    float inv[4];
#pragma unroll
    for (int i = 0; i < 4; ++i) inv[i] = 1.0f / lrow[i];
#pragma unroll
    for (int ct = 0; ct < 8; ++ct)
#pragma unroll
      for (int i = 0; i < 4; ++i) {
        const int srow = qt * 128 + wave * 16 + quad * 4 + i;
        qh[(size_t)srow * QKVROW + ct * 16 + l15] = f2bf(o[ct][i] * inv[i]);
      }
  }
}

// ---------------------------------------------------------------------------
// GEMM2: out[m,n] = sum_k ctx[m,k]*wob[n,k] + bo[n].  Same 2-deep counted-
// vmcnt pipeline as gemm1; A read from the q-slots of qkv (kh mapping).
// ---------------------------------------------------------------------------
__global__ __launch_bounds__(256) void gemm2(
    const unsigned short* __restrict__ A, const unsigned short* __restrict__ Bm,
    const float* __restrict__ bias, float* __restrict__ C) {
  __shared__ unsigned short As[2][128 * 64];
  __shared__ unsigned short Bs[2][128 * 64];
  const int tid = threadIdx.x;
  const int lane = tid & 63, wave = tid >> 6;
  const int l15 = lane & 15, quad = lane >> 4;
  const int m0 = blockIdx.y * 128, n0 = blockIdx.x * 128;
  const int wr = (wave >> 1) * 64, wc = (wave & 1) * 64;

  f32x4 acc[4][4];
#pragma unroll
  for (int r = 0; r < 4; ++r)
#pragma unroll
    for (int c = 0; c < 4; ++c) acc[r][c] = (f32x4){0.f, 0.f, 0.f, 0.f};

  auto stage = [&](int t, int b) {
    const int k0 = t * 64;
    const int kh = ((k0 >> 7) * 384) + (k0 & 127);  // ctx lives in q slots
#pragma unroll
    for (int i = 0; i < 4; ++i) {
      const int c0 = wave * 256 + i * 64;
      const int u = c0 + lane;
      const int row = u >> 3, cu = u & 7;
      const int cs = cu ^ (row & 7);
      async16(A + (size_t)(m0 + row) * QKVROW + kh + cs * 8, &As[b][c0 * 8]);
      async16(Bm + (size_t)(n0 + row) * 2048 + k0 + cs * 8, &Bs[b][c0 * 8]);
    }
  };

  stage(0, 0);
  stage(1, 1);

  for (int kt = 0; kt < 32; ++kt) {
    const int b = kt & 1;
    if (kt < 31) asm volatile("s_waitcnt vmcnt(8)" ::: "memory");
    else         asm volatile("s_waitcnt vmcnt(0)" ::: "memory");
    __builtin_amdgcn_s_barrier();
    __builtin_amdgcn_sched_barrier(0);

#pragma unroll
    for (int s = 0; s < 2; ++s) {
      bf16x8 af[4], bf[4];
#pragma unroll
      for (int r = 0; r < 4; ++r) {
        const int row = wr + r * 16 + l15;
        af[r] = *(const bf16x8*)&As[b][row * 64 + (((s * 4 + quad) ^ (row & 7)) << 3)];
      }
#pragma unroll
      for (int c = 0; c < 4; ++c) {
        const int row = wc + c * 16 + l15;
        bf[c] = *(const bf16x8*)&Bs[b][row * 64 + (((s * 4 + quad) ^ (row & 7)) << 3)];
      }
#pragma unroll
      for (int r = 0; r < 4; ++r)
#pragma unroll
        for (int c = 0; c < 4; ++c)
          acc[r][c] = __builtin_amdgcn_mfma_f32_16x16x32_bf16(af[r], bf[c], acc[r][c], 0, 0, 0);
    }

    asm volatile("s_waitcnt lgkmcnt(0)" ::: "memory");
    __builtin_amdgcn_sched_barrier(0);
    __builtin_amdgcn_s_barrier();
    __builtin_amdgcn_sched_barrier(0);
    if (kt + 2 < 32) stage(kt + 2, b);
  }

#pragma unroll
  for (int c = 0; c < 4; ++c) {
    const int col = n0 + wc + c * 16 + l15;
    const float bv = bias[col];
#pragma unroll
    for (int r = 0; r < 4; ++r) {
      const int row = m0 + wr + r * 16 + quad * 4;
#pragma unroll
      for (int i = 0; i < 4; ++i)
        C[(size_t)(row + i) * 2048 + col] = acc[r][c][i] + bv;
    }
  }
}

extern "C" void kernel_launch(void* const* d_in, const int* in_sizes, int n_in,
                              void* d_out, int out_size, void* d_ws, size_t ws_size,
                              hipStream_t stream) {
  const float* x    = (const float*)d_in[0];
  const float* wqkv = (const float*)d_in[1];
  const float* bqkv = (const float*)d_in[2];
  const float* wo   = (const float*)d_in[3];
  const float* bo   = (const float*)d_in[4];
  float* out = (float*)d_out;

  unsigned short* qkv = (unsigned short*)d_ws;            // 50.3 MB [4096][6144]
  unsigned short* Vt  = qkv + (size_t)M_ * QKVROW;        // 16.8 MB [b,h,hd,s]
  unsigned short* xb  = Vt  + (size_t)B_ * H_ * HD_ * S_; // 16.8 MB [4096][2048] bf16
  unsigned short* wb  = xb  + (size_t)M_ * 2048;          // 25.2 MB [6144][2048] bf16
  unsigned short* wob = wb  + (size_t)QKVROW * 2048;      //  8.4 MB [2048][2048] bf16
  float* tab = (float*)(wob + (size_t)2048 * 2048);       //  1.0 MB [2048][64][2]

  rope_table<<<dim3((S_ * 64) / 256), 256, 0, stream>>>(tab);
  f2bf3<<<dim3(2048), 256, 0, stream>>>(x, xb, (M_ * 2048) / 8,
                                        wqkv, wb, (QKVROW * 2048) / 8,
                                        wo, wob, (2048 * 2048) / 8);

  gemm1<<<dim3(QKVROW / 128, M_ / 128), 256, 0, stream>>>(xb, wb, bqkv, qkv);
  rope_vt<<<dim3(S_ / 64, H_, B_), 256, 0, stream>>>(qkv, Vt, tab);
  attn<<<dim3(8, B_ * H_), 512, 0, stream>>>(qkv, Vt);
  gemm2<<<dim3(2048 / 128, M_ / 128), 256, 0, stream>>>(qkv, wob, bo, out);
}

// Round 6
// 413.938 us; speedup vs baseline: 1.0129x; 1.0129x over previous
//
#include <hip/hip_runtime.h>

#define B_ 2
#define S_ 2048
#define H_ 16
#define HD_ 128
#define QKVROW 6144   // 3*2048, row length of qkv activation
#define M_ 4096       // B_*S_

typedef float f32x4 __attribute__((ext_vector_type(4)));
typedef __bf16 bf16x8 __attribute__((ext_vector_type(8)));
typedef unsigned short ushortx8 __attribute__((ext_vector_type(8)));

__device__ __forceinline__ float bf2f(unsigned short u) {
  union { unsigned u; float f; } v;
  v.u = ((unsigned)u) << 16;
  return v.f;
}
__device__ __forceinline__ unsigned short f2bf(float f) {
  union { __bf16 b; unsigned short u; } c;
  c.b = (__bf16)f;  // native v_cvt path
  return c.u;
}
// 8 contiguous fp32 -> 8 bf16 ushorts (vector loads + native cvt)
__device__ __forceinline__ ushortx8 cvt8(const float* f) {
  const f32x4 lo = *(const f32x4*)f;
  const f32x4 hi = *(const f32x4*)(f + 4);
  ushortx8 o;
#pragma unroll
  for (int t = 0; t < 4; ++t) o[t] = f2bf(lo[t]);
#pragma unroll
  for (int t = 0; t < 4; ++t) o[4 + t] = f2bf(hi[t]);
  return o;
}
// async global->LDS, 16B/lane. LDS dest = wave-uniform base + lane*16.
__device__ __forceinline__ void async16(const unsigned short* g, unsigned short* l) {
  __builtin_amdgcn_global_load_lds(
      (const __attribute__((address_space(1))) unsigned int*)g,
      (__attribute__((address_space(3))) unsigned int*)l, 16, 0, 0);
}

// ---------------------------------------------------------------------------
// One-time RoPE cos/sin table: tab[s][j] = {cos, sin}(s * base^(-j/64)).
// ---------------------------------------------------------------------------
__global__ __launch_bounds__(256) void rope_table(float* __restrict__ tab) {
  const int i = blockIdx.x * 256 + threadIdx.x;  // [0, 2048*64)
  const int s = i >> 6, t = i & 63;
  const float invf = expf(-(float)t * 0.14391156831212787f);  // ln(1e4)/64
  float sn, cs;
  sincosf((float)s * invf, &sn, &cs);
  tab[2 * i] = cs;
  tab[2 * i + 1] = sn;
}

// ---------------------------------------------------------------------------
// One-time fp32 -> bf16 conversion of x, Wqkv, wo in a single launch.
// ---------------------------------------------------------------------------
__global__ __launch_bounds__(256) void f2bf3(
    const float* __restrict__ a, unsigned short* __restrict__ da, int na8,
    const float* __restrict__ b, unsigned short* __restrict__ db, int nb8,
    const float* __restrict__ c, unsigned short* __restrict__ dc, int nc8) {
  const int ntot = na8 + nb8 + nc8;
  int i = blockIdx.x * 256 + threadIdx.x;
  const int stride = gridDim.x * 256;
  for (; i < ntot; i += stride) {
    const float* s;
    unsigned short* d;
    int off = i;
    if (off < na8) { s = a; d = da; }
    else if (off - na8 < nb8) { off -= na8; s = b; d = db; }
    else { off -= na8 + nb8; s = c; d = dc; }
    const ushortx8 o = cvt8(s + (size_t)off * 8);
    *(ushortx8*)&d[(size_t)off * 8] = o;
  }
}

// ---------------------------------------------------------------------------
// GEMM1: qkv[m,n] = sum_k xb[m,k]*wb[n,k] + b[n].  xb,wb bf16; C bf16.
// m97 structure + rule-21 swizzle (round-2/4 verified: 130 us, 0 conflicts).
// Pipelining attempts (r3 coarse 8-phase, r5 2-deep counted vmcnt) both
// regressed -- this 2-barrier schedule is the structure's sweet spot.
// ---------------------------------------------------------------------------
__global__ __launch_bounds__(256) void gemm1(
    const unsigned short* __restrict__ A, const unsigned short* __restrict__ Bm,
    const float* __restrict__ bias, unsigned short* __restrict__ C) {
  __shared__ unsigned short As[128 * 64];
  __shared__ unsigned short Bs[128 * 64];
  const int tid = threadIdx.x;
  const int lane = tid & 63, wave = tid >> 6;
  const int l15 = lane & 15, quad = lane >> 4;
  const int m0 = blockIdx.y * 128, n0 = blockIdx.x * 128;
  const int wr = (wave >> 1) * 64, wc = (wave & 1) * 64;

  f32x4 acc[4][4];
#pragma unroll
  for (int r = 0; r < 4; ++r)
#pragma unroll
    for (int c = 0; c < 4; ++c) acc[r][c] = (f32x4){0.f, 0.f, 0.f, 0.f};

  for (int k0 = 0; k0 < 2048; k0 += 64) {
    __syncthreads();  // prior iteration's frag reads done
#pragma unroll
    for (int i = 0; i < 4; ++i) {
      const int c0 = wave * 256 + i * 64;   // 16B-unit base within tile
      const int u = c0 + lane;
      const int row = u >> 3, cu = u & 7;   // 128 rows x 8 units
      const int cs = cu ^ (row & 7);        // pre-swizzled source column
      async16(A + (size_t)(m0 + row) * 2048 + k0 + cs * 8, &As[c0 * 8]);
      async16(Bm + (size_t)(n0 + row) * 2048 + k0 + cs * 8, &Bs[c0 * 8]);
    }
    __syncthreads();  // drains vmcnt -> tiles visible

#pragma unroll
    for (int s = 0; s < 2; ++s) {
      bf16x8 af[4], bf[4];
#pragma unroll
      for (int r = 0; r < 4; ++r) {
        const int row = wr + r * 16 + l15;
        af[r] = *(const bf16x8*)&As[row * 64 + (((s * 4 + quad) ^ (row & 7)) << 3)];
      }
#pragma unroll
      for (int c = 0; c < 4; ++c) {
        const int row = wc + c * 16 + l15;
        bf[c] = *(const bf16x8*)&Bs[row * 64 + (((s * 4 + quad) ^ (row & 7)) << 3)];
      }
#pragma unroll
      for (int r = 0; r < 4; ++r)
#pragma unroll
        for (int c = 0; c < 4; ++c)
          acc[r][c] = __builtin_amdgcn_mfma_f32_16x16x32_bf16(af[r], bf[c], acc[r][c], 0, 0, 0);
    }
  }

#pragma unroll
  for (int c = 0; c < 4; ++c) {
    const int col = n0 + wc + c * 16 + l15;
    const float bv = bias[col];
#pragma unroll
    for (int r = 0; r < 4; ++r) {
      const int row = m0 + wr + r * 16 + quad * 4;
#pragma unroll
      for (int i = 0; i < 4; ++i)
        C[(size_t)(row + i) * QKVROW + col] = f2bf(acc[r][c][i] + bv);
    }
  }
}

// ---------------------------------------------------------------------------
// In-place deinterleave+RoPE on q,k slots of qkv (q pre-scaled by hd^-0.5);
// Vt [b,h,hd,s] from the v slot. Trig from the precomputed table.
// ---------------------------------------------------------------------------
__global__ __launch_bounds__(256) void rope_vt(
    unsigned short* qkv, unsigned short* __restrict__ Vt,
    const float* __restrict__ tab) {
  __shared__ unsigned short vs[64 * 136];
  const int b = blockIdx.z, h = blockIdx.y, s0 = blockIdx.x * 64;
  const int tid = threadIdx.x;
  const int r = tid >> 2, cpart = (tid & 3) * 32;
  const int s = s0 + r;
  unsigned short* base = qkv + (size_t)(b * S_ + s) * QKVROW + h * 384;
  const int j0 = cpart >> 1;

  ushortx8 ivq[4], ivk[4], ivv[4];
#pragma unroll
  for (int i = 0; i < 4; ++i) {
    ivq[i] = *(const ushortx8*)&base[cpart + i * 8];
    ivk[i] = *(const ushortx8*)&base[128 + cpart + i * 8];
    ivv[i] = *(const ushortx8*)&base[256 + cpart + i * 8];
  }

  float cs[16], sn[16];
  {
    const f32x4* tr = (const f32x4*)&tab[(size_t)s * 128 + j0 * 2];
#pragma unroll
    for (int t = 0; t < 8; ++t) {
      const f32x4 v = tr[t];  // {cos,sin,cos,sin}
      cs[2 * t] = v[0]; sn[2 * t] = v[1];
      cs[2 * t + 1] = v[2]; sn[2 * t + 1] = v[3];
    }
  }

  __syncthreads();  // all reads of q/k rows done before anyone writes them

#pragma unroll
  for (int which = 0; which < 2; ++which) {
    const ushortx8* iv = (which == 0) ? ivq : ivk;
    const float scale = (which == 0) ? 0.08838834764831845f : 1.0f;
    ushortx8 o1a, o1b, o2a, o2b;
#pragma unroll
    for (int t = 0; t < 16; ++t) {
      const float x1 = bf2f(iv[(2 * t) >> 3][(2 * t) & 7]);
      const float x2 = bf2f(iv[(2 * t + 1) >> 3][(2 * t + 1) & 7]);
      const unsigned short r1 = f2bf((x1 * cs[t] - x2 * sn[t]) * scale);
      const unsigned short r2 = f2bf((x2 * cs[t] + x1 * sn[t]) * scale);
      if (t < 8) { o1a[t] = r1; o2a[t] = r2; }
      else       { o1b[t - 8] = r1; o2b[t - 8] = r2; }
    }
    unsigned short* out = base + which * 128;
    *(ushortx8*)&out[j0] = o1a;
    *(ushortx8*)&out[j0 + 8] = o1b;
    *(ushortx8*)&out[64 + j0] = o2a;
    *(ushortx8*)&out[64 + j0 + 8] = o2b;
  }

#pragma unroll
  for (int i = 0; i < 4; ++i)
    *(ushortx8*)&vs[r * 136 + cpart + i * 8] = ivv[i];
  __syncthreads();
  const size_t vtb = (size_t)(b * H_ + h) * HD_ * S_ + s0;
#pragma unroll
  for (int it = 0; it < 4; ++it) {
    const int a = tid + it * 256;
    const int d = a >> 3, sc = (a & 7) * 8;
    ushortx8 o;
#pragma unroll
    for (int t = 0; t < 8; ++t) o[t] = vs[(sc + t) * 136 + d];
    *(ushortx8*)&Vt[vtb + (size_t)d * S_ + sc] = o;
  }
}

// ---------------------------------------------------------------------------
// Flash attention v3, causal. grid (8, 2, 32), 256 threads (4 waves).
// Round-6 change: each former 8-wave block split into 2 independent
// half-blocks along q-rows (sub = blockIdx.y owns rows sub*64..+63 of the
// q-tile). 512 blocks -> 2-3 co-resident per CU: independent barrier groups
// hide each other's stalls. sub=0 also skips its final kv-tile
// (jN = 2qt+1+sub). All math / layouts otherwise unchanged.
// ---------------------------------------------------------------------------
__global__ __launch_bounds__(256) void attn(
    unsigned short* qkv, const unsigned short* __restrict__ Vt) {
  __shared__ unsigned short Ks[64 * 136];   // 17.4 KB
  __shared__ unsigned short Vs[128 * 72];   // 18.4 KB
  __shared__ unsigned short Ps[4 * 16 * 72];//  9.2 KB (per-wave strips)
  const int p = blockIdx.x, sub = blockIdx.y, bh = blockIdx.z;
  const int b = bh >> 4, h = bh & 15;
  const int tid = threadIdx.x, lane = tid & 63, wave = tid >> 6;
  const int l15 = lane & 15, quad = lane >> 4;

  unsigned short* qh = qkv + (size_t)b * S_ * QKVROW + h * 384;
  const unsigned short* Vb = Vt + (size_t)bh * HD_ * S_;
  unsigned short* Pw = &Ps[wave * 16 * 72];

  ushortx8 rk[4], rv[4];
  auto pref = [&](int j) {  // stage kv-64 tile j into regs (256 threads)
#pragma unroll
    for (int t = 0; t < 4; ++t) {
      const int uk = t * 256 + tid;
      const int krow = uk >> 4, kcu = uk & 15;  // 64 rows x 16 units
      rk[t] = *(const ushortx8*)(qh + (size_t)(j * 64 + krow) * QKVROW + 128 + kcu * 8);
      const int vrow = uk >> 3, vcu = uk & 7;   // 128 rows x 8 units
      rv[t] = *(const ushortx8*)(Vb + (size_t)vrow * S_ + j * 64 + vcu * 8);
    }
  };
  pref(0);

#pragma unroll
  for (int half = 0; half < 2; ++half) {
    const int qt = half ? 15 - p : p;   // short tile first, then long
    const int jN = 2 * qt + 1 + sub;    // kv-64 tiles needed for this half-tile
    const int r0 = qt * 128 + sub * 64 + wave * 16;  // first q-row of this wave

    bf16x8 aq[4];
#pragma unroll
    for (int ks = 0; ks < 4; ++ks)
      aq[ks] = *(const bf16x8*)&qh[(size_t)(r0 + l15) * QKVROW + ks * 32 + quad * 8];

    f32x4 o[8];
    float mrow[4], lrow[4];
#pragma unroll
    for (int ct = 0; ct < 8; ++ct) o[ct] = (f32x4){0.f, 0.f, 0.f, 0.f};
#pragma unroll
    for (int i = 0; i < 4; ++i) { mrow[i] = -1e30f; lrow[i] = 0.f; }

    for (int j = 0; j < jN; ++j) {
      __syncthreads();  // all waves done reading Ks/Vs of previous tile
#pragma unroll
      for (int t = 0; t < 4; ++t) {
        const int uk = t * 256 + tid;
        *(ushortx8*)&Ks[(uk >> 4) * 136 + (uk & 15) * 8] = rk[t];
        *(ushortx8*)&Vs[(uk >> 3) * 72 + (uk & 7) * 8] = rv[t];
      }
      __syncthreads();  // tiles visible

      const int jn = (j + 1 < jN) ? j + 1 : (half == 0 ? 0 : -1);
      if (jn >= 0) pref(jn);  // overlaps MFMA/softmax below

      // S = Q K^T over this kv-64 tile (Q pre-scaled by hd^-0.5)
      f32x4 sacc[4];
#pragma unroll
      for (int ct = 0; ct < 4; ++ct) sacc[ct] = (f32x4){0.f, 0.f, 0.f, 0.f};
#pragma unroll
      for (int ks = 0; ks < 4; ++ks) {
        bf16x8 bk[4];
#pragma unroll
        for (int ct = 0; ct < 4; ++ct)
          bk[ct] = *(const bf16x8*)&Ks[(ct * 16 + l15) * 136 + ks * 32 + quad * 8];
#pragma unroll
        for (int ct = 0; ct < 4; ++ct)
          sacc[ct] = __builtin_amdgcn_mfma_f32_16x16x32_bf16(aq[ks], bk[ct], sacc[ct], 0, 0, 0);
      }

      if (j >= 2 * qt) {  // diagonal region: mask gcol > grow
#pragma unroll
        for (int ct = 0; ct < 4; ++ct)
#pragma unroll
          for (int i = 0; i < 4; ++i) {
            const int grow = r0 + quad * 4 + i;
            const int gcol = j * 64 + ct * 16 + l15;
            if (gcol > grow) sacc[ct][i] = -1e30f;
          }
      }

      // online softmax (16 rows/wave = quad*4+i; reduce over 16 lanes)
#pragma unroll
      for (int i = 0; i < 4; ++i) {
        float m = sacc[0][i];
#pragma unroll
        for (int ct = 1; ct < 4; ++ct) m = fmaxf(m, sacc[ct][i]);
#pragma unroll
        for (int off = 1; off < 16; off <<= 1) m = fmaxf(m, __shfl_xor(m, off));
        const float mn = fmaxf(mrow[i], m);
        const float alpha = __expf(mrow[i] - mn);
        mrow[i] = mn;
        float rsum = 0.f;
#pragma unroll
        for (int ct = 0; ct < 4; ++ct) {
          const float pv = __expf(sacc[ct][i] - mn);
          sacc[ct][i] = pv;
          rsum += pv;
        }
#pragma unroll
        for (int off = 1; off < 16; off <<= 1) rsum += __shfl_xor(rsum, off);
        lrow[i] = lrow[i] * alpha + rsum;
#pragma unroll
        for (int ct = 0; ct < 8; ++ct) o[ct][i] *= alpha;
      }

      // P into wave-private strip (C-layout -> A-layout); no barrier needed
#pragma unroll
      for (int ct = 0; ct < 4; ++ct)
#pragma unroll
        for (int i = 0; i < 4; ++i)
          Pw[(quad * 4 + i) * 72 + ct * 16 + l15] = f2bf(sacc[ct][i]);

      // O += P * V
#pragma unroll
      for (int ks = 0; ks < 2; ++ks) {
        const bf16x8 ap = *(const bf16x8*)&Pw[l15 * 72 + ks * 32 + quad * 8];
        bf16x8 bv[8];
#pragma unroll
        for (int ct = 0; ct < 8; ++ct)
          bv[ct] = *(const bf16x8*)&Vs[(ct * 16 + l15) * 72 + ks * 32 + quad * 8];
#pragma unroll
        for (int ct = 0; ct < 8; ++ct)
          o[ct] = __builtin_amdgcn_mfma_f32_16x16x32_bf16(ap, bv[ct], o[ct], 0, 0, 0);
      }
    }

    // write ctx into the (consumed, block-private) q slot rows
    float inv[4];
#pragma unroll
    for (int i = 0; i < 4; ++i) inv[i] = 1.0f / lrow[i];
#pragma unroll
    for (int ct = 0; ct < 8; ++ct)
#pragma unroll
      for (int i = 0; i < 4; ++i) {
        const int srow = r0 + quad * 4 + i;
        qh[(size_t)srow * QKVROW + ct * 16 + l15] = f2bf(o[ct][i] * inv[i]);
      }
  }
}

// ---------------------------------------------------------------------------
// GEMM2: out[m,n] = sum_k ctx[m,k]*wob[n,k] + bo[n].  Both operands bf16,
// both staged via global_load_lds with rule-21 swizzle. (Round-2/4 verified.)
// ---------------------------------------------------------------------------
__global__ __launch_bounds__(256) void gemm2(
    const unsigned short* __restrict__ A, const unsigned short* __restrict__ Bm,
    const float* __restrict__ bias, float* __restrict__ C) {
  __shared__ unsigned short As[128 * 64];
  __shared__ unsigned short Bs[128 * 64];
  const int tid = threadIdx.x;
  const int lane = tid & 63, wave = tid >> 6;
  const int l15 = lane & 15, quad = lane >> 4;
  const int m0 = blockIdx.y * 128, n0 = blockIdx.x * 128;
  const int wr = (wave >> 1) * 64, wc = (wave & 1) * 64;

  f32x4 acc[4][4];
#pragma unroll
  for (int r = 0; r < 4; ++r)
#pragma unroll
    for (int c = 0; c < 4; ++c) acc[r][c] = (f32x4){0.f, 0.f, 0.f, 0.f};

  for (int k0 = 0; k0 < 2048; k0 += 64) {
    const int kh = ((k0 >> 7) * 384) + (k0 & 127);  // ctx lives in q slots
    __syncthreads();  // prior frag reads done
#pragma unroll
    for (int i = 0; i < 4; ++i) {
      const int c0 = wave * 256 + i * 64;
      const int u = c0 + lane;
      const int row = u >> 3, cu = u & 7;
      const int cs = cu ^ (row & 7);        // pre-swizzled source column
      async16(A + (size_t)(m0 + row) * QKVROW + kh + cs * 8, &As[c0 * 8]);
      async16(Bm + (size_t)(n0 + row) * 2048 + k0 + cs * 8, &Bs[c0 * 8]);
    }
    __syncthreads();  // drains vmcnt -> tiles visible

#pragma unroll
    for (int s = 0; s < 2; ++s) {
      bf16x8 af[4], bf[4];
#pragma unroll
      for (int r = 0; r < 4; ++r) {
        const int row = wr + r * 16 + l15;
        af[r] = *(const bf16x8*)&As[row * 64 + (((s * 4 + quad) ^ (row & 7)) << 3)];
      }
#pragma unroll
      for (int c = 0; c < 4; ++c) {
        const int row = wc + c * 16 + l15;
        bf[c] = *(const bf16x8*)&Bs[row * 64 + (((s * 4 + quad) ^ (row & 7)) << 3)];
      }
#pragma unroll
      for (int r = 0; r < 4; ++r)
#pragma unroll
        for (int c = 0; c < 4; ++c)
          acc[r][c] = __builtin_amdgcn_mfma_f32_16x16x32_bf16(af[r], bf[c], acc[r][c], 0, 0, 0);
    }
  }

#pragma unroll
  for (int c = 0; c < 4; ++c) {
    const int col = n0 + wc + c * 16 + l15;
    const float bv = bias[col];
#pragma unroll
    for (int r = 0; r < 4; ++r) {
      const int row = m0 + wr + r * 16 + quad * 4;
#pragma unroll
      for (int i = 0; i < 4; ++i)
        C[(size_t)(row + i) * 2048 + col] = acc[r][c][i] + bv;
    }
  }
}

extern "C" void kernel_launch(void* const* d_in, const int* in_sizes, int n_in,
                              void* d_out, int out_size, void* d_ws, size_t ws_size,
                              hipStream_t stream) {
  const float* x    = (const float*)d_in[0];
  const float* wqkv = (const float*)d_in[1];
  const float* bqkv = (const float*)d_in[2];
  const float* wo   = (const float*)d_in[3];
  const float* bo   = (const float*)d_in[4];
  float* out = (float*)d_out;

  unsigned short* qkv = (unsigned short*)d_ws;            // 50.3 MB [4096][6144]
  unsigned short* Vt  = qkv + (size_t)M_ * QKVROW;        // 16.8 MB [b,h,hd,s]
  unsigned short* xb  = Vt  + (size_t)B_ * H_ * HD_ * S_; // 16.8 MB [4096][2048] bf16
  unsigned short* wb  = xb  + (size_t)M_ * 2048;          // 25.2 MB [6144][2048] bf16
  unsigned short* wob = wb  + (size_t)QKVROW * 2048;      //  8.4 MB [2048][2048] bf16
  float* tab = (float*)(wob + (size_t)2048 * 2048);       //  1.0 MB [2048][64][2]

  rope_table<<<dim3((S_ * 64) / 256), 256, 0, stream>>>(tab);
  f2bf3<<<dim3(2048), 256, 0, stream>>>(x, xb, (M_ * 2048) / 8,
                                        wqkv, wb, (QKVROW * 2048) / 8,
                                        wo, wob, (2048 * 2048) / 8);

  gemm1<<<dim3(QKVROW / 128, M_ / 128), 256, 0, stream>>>(xb, wb, bqkv, qkv);
  rope_vt<<<dim3(S_ / 64, H_, B_), 256, 0, stream>>>(qkv, Vt, tab);
  attn<<<dim3(8, 2, B_ * H_), 256, 0, stream>>>(qkv, Vt);
  gemm2<<<dim3(2048 / 128, M_ / 128), 256, 0, stream>>>(qkv, wob, bo, out);
}

// Round 7
// 402.563 us; speedup vs baseline: 1.0415x; 1.0283x over previous
//
#include <hip/hip_runtime.h>

#define B_ 2
#define S_ 2048
#define H_ 16
#define HD_ 128
#define QKVROW 6144   // 3*2048, row length of qkv activation
#define M_ 4096       // B_*S_

typedef float f32x4 __attribute__((ext_vector_type(4)));
typedef __bf16 bf16x8 __attribute__((ext_vector_type(8)));
typedef unsigned short ushortx8 __attribute__((ext_vector_type(8)));

__device__ __forceinline__ float bf2f(unsigned short u) {
  union { unsigned u; float f; } v;
  v.u = ((unsigned)u) << 16;
  return v.f;
}
__device__ __forceinline__ unsigned short f2bf(float f) {
  union { __bf16 b; unsigned short u; } c;
  c.b = (__bf16)f;  // native v_cvt path
  return c.u;
}
// 8 contiguous fp32 -> 8 bf16 ushorts (vector loads + native cvt)
__device__ __forceinline__ ushortx8 cvt8(const float* f) {
  const f32x4 lo = *(const f32x4*)f;
  const f32x4 hi = *(const f32x4*)(f + 4);
  ushortx8 o;
#pragma unroll
  for (int t = 0; t < 4; ++t) o[t] = f2bf(lo[t]);
#pragma unroll
  for (int t = 0; t < 4; ++t) o[4 + t] = f2bf(hi[t]);
  return o;
}
// async global->LDS, 16B/lane. LDS dest = wave-uniform base + lane*16.
__device__ __forceinline__ void async16(const unsigned short* g, unsigned short* l) {
  __builtin_amdgcn_global_load_lds(
      (const __attribute__((address_space(1))) unsigned int*)g,
      (__attribute__((address_space(3))) unsigned int*)l, 16, 0, 0);
}

// ---------------------------------------------------------------------------
// One-time RoPE cos/sin table: tab[s][j] = {cos, sin}(s * base^(-j/64)).
// ---------------------------------------------------------------------------
__global__ __launch_bounds__(256) void rope_table(float* __restrict__ tab) {
  const int i = blockIdx.x * 256 + threadIdx.x;  // [0, 2048*64)
  const int s = i >> 6, t = i & 63;
  const float invf = expf(-(float)t * 0.14391156831212787f);  // ln(1e4)/64
  float sn, cs;
  sincosf((float)s * invf, &sn, &cs);
  tab[2 * i] = cs;
  tab[2 * i + 1] = sn;
}

// ---------------------------------------------------------------------------
// One-time fp32 -> bf16 conversion of x, Wqkv, wo in a single launch.
// ---------------------------------------------------------------------------
__global__ __launch_bounds__(256) void f2bf3(
    const float* __restrict__ a, unsigned short* __restrict__ da, int na8,
    const float* __restrict__ b, unsigned short* __restrict__ db, int nb8,
    const float* __restrict__ c, unsigned short* __restrict__ dc, int nc8) {
  const int ntot = na8 + nb8 + nc8;
  int i = blockIdx.x * 256 + threadIdx.x;
  const int stride = gridDim.x * 256;
  for (; i < ntot; i += stride) {
    const float* s;
    unsigned short* d;
    int off = i;
    if (off < na8) { s = a; d = da; }
    else if (off - na8 < nb8) { off -= na8; s = b; d = db; }
    else { off -= na8 + nb8; s = c; d = dc; }
    const ushortx8 o = cvt8(s + (size_t)off * 8);
    *(ushortx8*)&d[(size_t)off * 8] = o;
  }
}

// ---------------------------------------------------------------------------
// GEMM1: qkv[m,n] = sum_k xb[m,k]*wb[n,k] + b[n].  xb,wb bf16; C bf16.
// m97 structure + rule-21 swizzle (round-2/4 verified: 130 us, 0 conflicts).
// Pipelining attempts (r3 coarse 8-phase, r5 2-deep counted vmcnt) both
// regressed -- this 2-barrier schedule is the structure's sweet spot.
// ---------------------------------------------------------------------------
__global__ __launch_bounds__(256) void gemm1(
    const unsigned short* __restrict__ A, const unsigned short* __restrict__ Bm,
    const float* __restrict__ bias, unsigned short* __restrict__ C) {
  __shared__ unsigned short As[128 * 64];
  __shared__ unsigned short Bs[128 * 64];
  const int tid = threadIdx.x;
  const int lane = tid & 63, wave = tid >> 6;
  const int l15 = lane & 15, quad = lane >> 4;
  const int m0 = blockIdx.y * 128, n0 = blockIdx.x * 128;
  const int wr = (wave >> 1) * 64, wc = (wave & 1) * 64;

  f32x4 acc[4][4];
#pragma unroll
  for (int r = 0; r < 4; ++r)
#pragma unroll
    for (int c = 0; c < 4; ++c) acc[r][c] = (f32x4){0.f, 0.f, 0.f, 0.f};

  for (int k0 = 0; k0 < 2048; k0 += 64) {
    __syncthreads();  // prior iteration's frag reads done
#pragma unroll
    for (int i = 0; i < 4; ++i) {
      const int c0 = wave * 256 + i * 64;   // 16B-unit base within tile
      const int u = c0 + lane;
      const int row = u >> 3, cu = u & 7;   // 128 rows x 8 units
      const int cs = cu ^ (row & 7);        // pre-swizzled source column
      async16(A + (size_t)(m0 + row) * 2048 + k0 + cs * 8, &As[c0 * 8]);
      async16(Bm + (size_t)(n0 + row) * 2048 + k0 + cs * 8, &Bs[c0 * 8]);
    }
    __syncthreads();  // drains vmcnt -> tiles visible

#pragma unroll
    for (int s = 0; s < 2; ++s) {
      bf16x8 af[4], bf[4];
#pragma unroll
      for (int r = 0; r < 4; ++r) {
        const int row = wr + r * 16 + l15;
        af[r] = *(const bf16x8*)&As[row * 64 + (((s * 4 + quad) ^ (row & 7)) << 3)];
      }
#pragma unroll
      for (int c = 0; c < 4; ++c) {
        const int row = wc + c * 16 + l15;
        bf[c] = *(const bf16x8*)&Bs[row * 64 + (((s * 4 + quad) ^ (row & 7)) << 3)];
      }
#pragma unroll
      for (int r = 0; r < 4; ++r)
#pragma unroll
        for (int c = 0; c < 4; ++c)
          acc[r][c] = __builtin_amdgcn_mfma_f32_16x16x32_bf16(af[r], bf[c], acc[r][c], 0, 0, 0);
    }
  }

#pragma unroll
  for (int c = 0; c < 4; ++c) {
    const int col = n0 + wc + c * 16 + l15;
    const float bv = bias[col];
#pragma unroll
    for (int r = 0; r < 4; ++r) {
      const int row = m0 + wr + r * 16 + quad * 4;
#pragma unroll
      for (int i = 0; i < 4; ++i)
        C[(size_t)(row + i) * QKVROW + col] = f2bf(acc[r][c][i] + bv);
    }
  }
}

// ---------------------------------------------------------------------------
// In-place deinterleave+RoPE on q,k slots of qkv (q pre-scaled by hd^-0.5);
// Vt [b,h,hd,s] from the v slot. Trig from the precomputed table.
// ---------------------------------------------------------------------------
__global__ __launch_bounds__(256) void rope_vt(
    unsigned short* qkv, unsigned short* __restrict__ Vt,
    const float* __restrict__ tab) {
  __shared__ unsigned short vs[64 * 136];
  const int b = blockIdx.z, h = blockIdx.y, s0 = blockIdx.x * 64;
  const int tid = threadIdx.x;
  const int r = tid >> 2, cpart = (tid & 3) * 32;
  const int s = s0 + r;
  unsigned short* base = qkv + (size_t)(b * S_ + s) * QKVROW + h * 384;
  const int j0 = cpart >> 1;

  ushortx8 ivq[4], ivk[4], ivv[4];
#pragma unroll
  for (int i = 0; i < 4; ++i) {
    ivq[i] = *(const ushortx8*)&base[cpart + i * 8];
    ivk[i] = *(const ushortx8*)&base[128 + cpart + i * 8];
    ivv[i] = *(const ushortx8*)&base[256 + cpart + i * 8];
  }

  float cs[16], sn[16];
  {
    const f32x4* tr = (const f32x4*)&tab[(size_t)s * 128 + j0 * 2];
#pragma unroll
    for (int t = 0; t < 8; ++t) {
      const f32x4 v = tr[t];  // {cos,sin,cos,sin}
      cs[2 * t] = v[0]; sn[2 * t] = v[1];
      cs[2 * t + 1] = v[2]; sn[2 * t + 1] = v[3];
    }
  }

  __syncthreads();  // all reads of q/k rows done before anyone writes them

#pragma unroll
  for (int which = 0; which < 2; ++which) {
    const ushortx8* iv = (which == 0) ? ivq : ivk;
    const float scale = (which == 0) ? 0.08838834764831845f : 1.0f;
    ushortx8 o1a, o1b, o2a, o2b;
#pragma unroll
    for (int t = 0; t < 16; ++t) {
      const float x1 = bf2f(iv[(2 * t) >> 3][(2 * t) & 7]);
      const float x2 = bf2f(iv[(2 * t + 1) >> 3][(2 * t + 1) & 7]);
      const unsigned short r1 = f2bf((x1 * cs[t] - x2 * sn[t]) * scale);
      const unsigned short r2 = f2bf((x2 * cs[t] + x1 * sn[t]) * scale);
      if (t < 8) { o1a[t] = r1; o2a[t] = r2; }
      else       { o1b[t - 8] = r1; o2b[t - 8] = r2; }
    }
    unsigned short* out = base + which * 128;
    *(ushortx8*)&out[j0] = o1a;
    *(ushortx8*)&out[j0 + 8] = o1b;
    *(ushortx8*)&out[64 + j0] = o2a;
    *(ushortx8*)&out[64 + j0 + 8] = o2b;
  }

#pragma unroll
  for (int i = 0; i < 4; ++i)
    *(ushortx8*)&vs[r * 136 + cpart + i * 8] = ivv[i];
  __syncthreads();
  const size_t vtb = (size_t)(b * H_ + h) * HD_ * S_ + s0;
#pragma unroll
  for (int it = 0; it < 4; ++it) {
    const int a = tid + it * 256;
    const int d = a >> 3, sc = (a & 7) * 8;
    ushortx8 o;
#pragma unroll
    for (int t = 0; t < 8; ++t) o[t] = vs[(sc + t) * 136 + d];
    *(ushortx8*)&Vt[vtb + (size_t)d * S_ + sc] = o;
  }
}

// ---------------------------------------------------------------------------
// Flash attention v3, causal. grid (32, 8, 2), 256 threads (4 waves).
// Round-7 changes:
//  * grid permuted so bh = blockIdx.x: the 16 blocks sharing one head's K/V
//    have linear-id stride 32 (== 0 mod 8 XCDs) -> all land on ONE XCD;
//    4 bh x 1MB K/V = 4MB fits that XCD's L2.
//  * deferred-sum softmax: lrow kept as per-lane partial (alpha uniform per
//    16-lane row group), 16-lane sum reduction once per q-tile, not per
//    kv-tile (-16 shfl/tile).
//  * defer-max (T13, THR=8): skip o-rescale pass when max growth bounded.
//  * s_setprio(1) around QK^T and PV MFMA clusters (T5).
// ---------------------------------------------------------------------------
__global__ __launch_bounds__(256) void attn(
    unsigned short* qkv, const unsigned short* __restrict__ Vt) {
  __shared__ unsigned short Ks[64 * 136];   // 17.4 KB
  __shared__ unsigned short Vs[128 * 72];   // 18.4 KB
  __shared__ unsigned short Ps[4 * 16 * 72];//  9.2 KB (per-wave strips)
  const int bh = blockIdx.x, p = blockIdx.y, sub = blockIdx.z;
  const int b = bh >> 4, h = bh & 15;
  const int tid = threadIdx.x, lane = tid & 63, wave = tid >> 6;
  const int l15 = lane & 15, quad = lane >> 4;

  unsigned short* qh = qkv + (size_t)b * S_ * QKVROW + h * 384;
  const unsigned short* Vb = Vt + (size_t)bh * HD_ * S_;
  unsigned short* Pw = &Ps[wave * 16 * 72];

  ushortx8 rk[4], rv[4];
  auto pref = [&](int j) {  // stage kv-64 tile j into regs (256 threads)
#pragma unroll
    for (int t = 0; t < 4; ++t) {
      const int uk = t * 256 + tid;
      const int krow = uk >> 4, kcu = uk & 15;  // 64 rows x 16 units
      rk[t] = *(const ushortx8*)(qh + (size_t)(j * 64 + krow) * QKVROW + 128 + kcu * 8);
      const int vrow = uk >> 3, vcu = uk & 7;   // 128 rows x 8 units
      rv[t] = *(const ushortx8*)(Vb + (size_t)vrow * S_ + j * 64 + vcu * 8);
    }
  };
  pref(0);

#pragma unroll
  for (int half = 0; half < 2; ++half) {
    const int qt = half ? 15 - p : p;   // short tile first, then long
    const int jN = 2 * qt + 1 + sub;    // kv-64 tiles needed for this half-tile
    const int r0 = qt * 128 + sub * 64 + wave * 16;  // first q-row of this wave

    bf16x8 aq[4];
#pragma unroll
    for (int ks = 0; ks < 4; ++ks)
      aq[ks] = *(const bf16x8*)&qh[(size_t)(r0 + l15) * QKVROW + ks * 32 + quad * 8];

    f32x4 o[8];
    float mrow[4], lpart[4];
#pragma unroll
    for (int ct = 0; ct < 8; ++ct) o[ct] = (f32x4){0.f, 0.f, 0.f, 0.f};
#pragma unroll
    for (int i = 0; i < 4; ++i) { mrow[i] = -1e30f; lpart[i] = 0.f; }

    for (int j = 0; j < jN; ++j) {
      __syncthreads();  // all waves done reading Ks/Vs of previous tile
#pragma unroll
      for (int t = 0; t < 4; ++t) {
        const int uk = t * 256 + tid;
        *(ushortx8*)&Ks[(uk >> 4) * 136 + (uk & 15) * 8] = rk[t];
        *(ushortx8*)&Vs[(uk >> 3) * 72 + (uk & 7) * 8] = rv[t];
      }
      __syncthreads();  // tiles visible

      const int jn = (j + 1 < jN) ? j + 1 : (half == 0 ? 0 : -1);
      if (jn >= 0) pref(jn);  // overlaps MFMA/softmax below

      // S = Q K^T over this kv-64 tile (Q pre-scaled by hd^-0.5)
      f32x4 sacc[4];
#pragma unroll
      for (int ct = 0; ct < 4; ++ct) sacc[ct] = (f32x4){0.f, 0.f, 0.f, 0.f};
      __builtin_amdgcn_s_setprio(1);
#pragma unroll
      for (int ks = 0; ks < 4; ++ks) {
        bf16x8 bk[4];
#pragma unroll
        for (int ct = 0; ct < 4; ++ct)
          bk[ct] = *(const bf16x8*)&Ks[(ct * 16 + l15) * 136 + ks * 32 + quad * 8];
#pragma unroll
        for (int ct = 0; ct < 4; ++ct)
          sacc[ct] = __builtin_amdgcn_mfma_f32_16x16x32_bf16(aq[ks], bk[ct], sacc[ct], 0, 0, 0);
      }
      __builtin_amdgcn_s_setprio(0);

      if (j >= 2 * qt) {  // diagonal region: mask gcol > grow
#pragma unroll
        for (int ct = 0; ct < 4; ++ct)
#pragma unroll
          for (int i = 0; i < 4; ++i) {
            const int grow = r0 + quad * 4 + i;
            const int gcol = j * 64 + ct * 16 + l15;
            if (gcol > grow) sacc[ct][i] = -1e30f;
          }
      }

      // per-row tile max (uniform within each 16-lane row group after reduce)
      float tmax[4];
#pragma unroll
      for (int i = 0; i < 4; ++i) {
        float m = fmaxf(fmaxf(sacc[0][i], sacc[1][i]), fmaxf(sacc[2][i], sacc[3][i]));
#pragma unroll
        for (int off = 1; off < 16; off <<= 1) m = fmaxf(m, __shfl_xor(m, off));
        tmax[i] = m;
      }
      // defer-max: only rescale when some row's max grew past THR=8
      bool need = false;
#pragma unroll
      for (int i = 0; i < 4; ++i) need = need || (tmax[i] > mrow[i] + 8.f);
      if (__any(need)) {
#pragma unroll
        for (int i = 0; i < 4; ++i) {
          const float mn = fmaxf(mrow[i], tmax[i]);
          const float alpha = __expf(mrow[i] - mn);
          mrow[i] = mn;
          lpart[i] *= alpha;
#pragma unroll
          for (int ct = 0; ct < 8; ++ct) o[ct][i] *= alpha;
        }
      }
      // P = exp(S - mrow); accumulate per-lane partial row sums
#pragma unroll
      for (int i = 0; i < 4; ++i) {
        float rs = 0.f;
#pragma unroll
        for (int ct = 0; ct < 4; ++ct) {
          const float pv = __expf(sacc[ct][i] - mrow[i]);
          sacc[ct][i] = pv;
          rs += pv;
        }
        lpart[i] += rs;
      }

      // P into wave-private strip (C-layout -> A-layout); no barrier needed
#pragma unroll
      for (int ct = 0; ct < 4; ++ct)
#pragma unroll
        for (int i = 0; i < 4; ++i)
          Pw[(quad * 4 + i) * 72 + ct * 16 + l15] = f2bf(sacc[ct][i]);

      // O += P * V
      __builtin_amdgcn_s_setprio(1);
#pragma unroll
      for (int ks = 0; ks < 2; ++ks) {
        const bf16x8 ap = *(const bf16x8*)&Pw[l15 * 72 + ks * 32 + quad * 8];
        bf16x8 bv[8];
#pragma unroll
        for (int ct = 0; ct < 8; ++ct)
          bv[ct] = *(const bf16x8*)&Vs[(ct * 16 + l15) * 72 + ks * 32 + quad * 8];
#pragma unroll
        for (int ct = 0; ct < 8; ++ct)
          o[ct] = __builtin_amdgcn_mfma_f32_16x16x32_bf16(ap, bv[ct], o[ct], 0, 0, 0);
      }
      __builtin_amdgcn_s_setprio(0);
    }

    // final 16-lane sum reduction (once per q-tile), then write ctx
    float inv[4];
#pragma unroll
    for (int i = 0; i < 4; ++i) {
      float l = lpart[i];
#pragma unroll
      for (int off = 1; off < 16; off <<= 1) l += __shfl_xor(l, off);
      inv[i] = 1.0f / l;
    }
#pragma unroll
    for (int ct = 0; ct < 8; ++ct)
#pragma unroll
      for (int i = 0; i < 4; ++i) {
        const int srow = r0 + quad * 4 + i;
        qh[(size_t)srow * QKVROW + ct * 16 + l15] = f2bf(o[ct][i] * inv[i]);
      }
  }
}

// ---------------------------------------------------------------------------
// GEMM2: out[m,n] = sum_k ctx[m,k]*wob[n,k] + bo[n].  Both operands bf16,
// both staged via global_load_lds with rule-21 swizzle. (Round-2/4 verified.)
// ---------------------------------------------------------------------------
__global__ __launch_bounds__(256) void gemm2(
    const unsigned short* __restrict__ A, const unsigned short* __restrict__ Bm,
    const float* __restrict__ bias, float* __restrict__ C) {
  __shared__ unsigned short As[128 * 64];
  __shared__ unsigned short Bs[128 * 64];
  const int tid = threadIdx.x;
  const int lane = tid & 63, wave = tid >> 6;
  const int l15 = lane & 15, quad = lane >> 4;
  const int m0 = blockIdx.y * 128, n0 = blockIdx.x * 128;
  const int wr = (wave >> 1) * 64, wc = (wave & 1) * 64;

  f32x4 acc[4][4];
#pragma unroll
  for (int r = 0; r < 4; ++r)
#pragma unroll
    for (int c = 0; c < 4; ++c) acc[r][c] = (f32x4){0.f, 0.f, 0.f, 0.f};

  for (int k0 = 0; k0 < 2048; k0 += 64) {
    const int kh = ((k0 >> 7) * 384) + (k0 & 127);  // ctx lives in q slots
    __syncthreads();  // prior frag reads done
#pragma unroll
    for (int i = 0; i < 4; ++i) {
      const int c0 = wave * 256 + i * 64;
      const int u = c0 + lane;
      const int row = u >> 3, cu = u & 7;
      const int cs = cu ^ (row & 7);        // pre-swizzled source column
      async16(A + (size_t)(m0 + row) * QKVROW + kh + cs * 8, &As[c0 * 8]);
      async16(Bm + (size_t)(n0 + row) * 2048 + k0 + cs * 8, &Bs[c0 * 8]);
    }
    __syncthreads();  // drains vmcnt -> tiles visible

#pragma unroll
    for (int s = 0; s < 2; ++s) {
      bf16x8 af[4], bf[4];
#pragma unroll
      for (int r = 0; r < 4; ++r) {
        const int row = wr + r * 16 + l15;
        af[r] = *(const bf16x8*)&As[row * 64 + (((s * 4 + quad) ^ (row & 7)) << 3)];
      }
#pragma unroll
      for (int c = 0; c < 4; ++c) {
        const int row = wc + c * 16 + l15;
        bf[c] = *(const bf16x8*)&Bs[row * 64 + (((s * 4 + quad) ^ (row & 7)) << 3)];
      }
#pragma unroll
      for (int r = 0; r < 4; ++r)
#pragma unroll
        for (int c = 0; c < 4; ++c)
          acc[r][c] = __builtin_amdgcn_mfma_f32_16x16x32_bf16(af[r], bf[c], acc[r][c], 0, 0, 0);
    }
  }

#pragma unroll
  for (int c = 0; c < 4; ++c) {
    const int col = n0 + wc + c * 16 + l15;
    const float bv = bias[col];
#pragma unroll
    for (int r = 0; r < 4; ++r) {
      const int row = m0 + wr + r * 16 + quad * 4;
#pragma unroll
      for (int i = 0; i < 4; ++i)
        C[(size_t)(row + i) * 2048 + col] = acc[r][c][i] + bv;
    }
  }
}

extern "C" void kernel_launch(void* const* d_in, const int* in_sizes, int n_in,
                              void* d_out, int out_size, void* d_ws, size_t ws_size,
                              hipStream_t stream) {
  const float* x    = (const float*)d_in[0];
  const float* wqkv = (const float*)d_in[1];
  const float* bqkv = (const float*)d_in[2];
  const float* wo   = (const float*)d_in[3];
  const float* bo   = (const float*)d_in[4];
  float* out = (float*)d_out;

  unsigned short* qkv = (unsigned short*)d_ws;            // 50.3 MB [4096][6144]
  unsigned short* Vt  = qkv + (size_t)M_ * QKVROW;        // 16.8 MB [b,h,hd,s]
  unsigned short* xb  = Vt  + (size_t)B_ * H_ * HD_ * S_; // 16.8 MB [4096][2048] bf16
  unsigned short* wb  = xb  + (size_t)M_ * 2048;          // 25.2 MB [6144][2048] bf16
  unsigned short* wob = wb  + (size_t)QKVROW * 2048;      //  8.4 MB [2048][2048] bf16
  float* tab = (float*)(wob + (size_t)2048 * 2048);       //  1.0 MB [2048][64][2]

  rope_table<<<dim3((S_ * 64) / 256), 256, 0, stream>>>(tab);
  f2bf3<<<dim3(2048), 256, 0, stream>>>(x, xb, (M_ * 2048) / 8,
                                        wqkv, wb, (QKVROW * 2048) / 8,
                                        wo, wob, (2048 * 2048) / 8);

  gemm1<<<dim3(QKVROW / 128, M_ / 128), 256, 0, stream>>>(xb, wb, bqkv, qkv);
  rope_vt<<<dim3(S_ / 64, H_, B_), 256, 0, stream>>>(qkv, Vt, tab);
  attn<<<dim3(B_ * H_, 8, 2), 256, 0, stream>>>(qkv, Vt);
  gemm2<<<dim3(2048 / 128, M_ / 128), 256, 0, stream>>>(qkv, wob, bo, out);
}